// Round 8
// baseline (985.762 us; speedup 1.0000x reference)
//
#include <hip/hip_runtime.h>
#include <math.h>

// ---------------------------------------------------------------------------
// FGAT round 8: L2-capacity engineering.
//   - fill_perm3 (range-partitioned) now also scatters src_s/dst_s (regions
//     stay L2-local); expand_e only gathers+packs e.
//   - hh stored as 4 head-planes (3.2 MB each, fits one XCD L2).
//     node_agg_head: head = (blockIdx%8)>>1 ~ XCD pair affinity; 16 lanes per
//     edge, 4 edges in flight; bf16 per-head outputs; combine kernel does
//     head-sum + ELU + states. Correctness independent of block->XCD mapping.
//   - states/outh bf16 to hold workspace at ~116 MB.
// ---------------------------------------------------------------------------

static __device__ inline unsigned short f2bf(float f) {
  unsigned x = __float_as_uint(f);
  unsigned r = x + 0x7fffu + ((x >> 16) & 1u);   // round-to-nearest-even
  return (unsigned short)(r >> 16);
}
static __device__ inline unsigned pack2bf(float lo, float hi) {
  return (unsigned)f2bf(lo) | ((unsigned)f2bf(hi) << 16);
}
static __device__ inline float bf2f(unsigned short u) {
  return __uint_as_float(((unsigned)u) << 16);
}
static __device__ inline float bf_lo(unsigned u) {
  return __uint_as_float(u << 16);
}
static __device__ inline float bf_hi(unsigned u) {
  return __uint_as_float(u & 0xffff0000u);
}

// ---------------- sort-building kernels ------------------------------------

__global__ void zero_ints(int* __restrict__ p, int n) {
  int i = blockIdx.x * blockDim.x + threadIdx.x;
  if (i < n) p[i] = 0;
}

__global__ void histogram(const int* __restrict__ dst, int* __restrict__ hist,
                          int n_edges) {
  int e = blockIdx.x * blockDim.x + threadIdx.x;
  if (e < n_edges) atomicAdd(&hist[dst[e]], 1);
}

__global__ void scan_block(const int* __restrict__ hist, int* __restrict__ partial,
                           int* __restrict__ blocksum, int n) {
  __shared__ int buf[1024];
  int tid = threadIdx.x;
  int g = blockIdx.x * 1024 + tid;
  int v = (g < n) ? hist[g] : 0;
  buf[tid] = v;
  __syncthreads();
  for (int off = 1; off < 1024; off <<= 1) {
    int t = (tid >= off) ? buf[tid - off] : 0;
    __syncthreads();
    buf[tid] += t;
    __syncthreads();
  }
  if (g < n) partial[g] = buf[tid] - v;       // exclusive within chunk
  if (tid == 1023) blocksum[blockIdx.x] = buf[1023];
}

__global__ void scan_sums(int* __restrict__ blocksum, int nb) {
  if (threadIdx.x == 0 && blockIdx.x == 0) {
    int run = 0;
    for (int i = 0; i < nb; i++) {
      int t = blocksum[i];
      blocksum[i] = run;
      run += t;
    }
    blocksum[nb] = run;
  }
}

__global__ void scan_add(int* __restrict__ partial /* -> row_off */,
                         const int* __restrict__ blocksum,
                         int* __restrict__ cursor, int n, int nb) {
  int g = blockIdx.x * blockDim.x + threadIdx.x;
  if (g < n) {
    int val = partial[g] + blocksum[g >> 10];
    partial[g] = val;
    cursor[g] = val;
  }
  if (g == 0) partial[n] = blocksum[nb];
}

// Range-partitioned fill: also writes src_s/dst_s (scatter regions per range
// ~2.4 MB -> L2-local under the blockIdx%8 ~ XCD heuristic).
#define FILL_NR 8
__global__ void fill_perm3(const int* __restrict__ dst, const int* __restrict__ src,
                           int* __restrict__ cursor, int* __restrict__ perm,
                           int* __restrict__ src_s, int* __restrict__ dst_s,
                           int n_edges, int seg) {
  int range = blockIdx.x % FILL_NR;
  int group = blockIdx.x / FILL_NR;
  int ngroups = gridDim.x / FILL_NR;
  int lo = range * seg;
  int hi = lo + seg;
  int stride = ngroups * blockDim.x;
  for (int k = group * blockDim.x + threadIdx.x; k < n_edges; k += stride) {
    int d = dst[k];
    if (d >= lo && d < hi) {
      int p = atomicAdd(&cursor[d], 1);
      perm[p] = k;
      src_s[p] = src[k];
      dst_s[p] = d;
    }
  }
}

// Gather e through perm, pack to bf16x8, write coalesced.
__global__ void expand_e(const int* __restrict__ perm, const float* __restrict__ e,
                         uint4* __restrict__ e_s, int n_edges) {
  int k = blockIdx.x * blockDim.x + threadIdx.x;
  if (k >= n_edges) return;
  int eid = perm[k];
  const float4* ep = (const float4*)(e + (size_t)eid * 8);
  float4 a = ep[0], b = ep[1];
  uint4 r;
  r.x = pack2bf(a.x, a.y); r.y = pack2bf(a.z, a.w);
  r.z = pack2bf(b.x, b.y); r.w = pack2bf(b.z, b.w);
  e_s[k] = r;
}

// ---------------- per-layer kernels ----------------------------------------

// One 64-lane wave per node; bf16 outputs. hh written head-sliced:
// plane h holds (N x 32) bf16 = 3.2 MB (fits one XCD L2).
__global__ void node_proj(const float* __restrict__ h,
                          const float* __restrict__ Wni,
                          const float* __restrict__ Wnj,
                          const float* __restrict__ Wnode,
                          const float* __restrict__ bE,
                          unsigned short* __restrict__ fni,
                          unsigned short* __restrict__ cdst,
                          unsigned short* __restrict__ hh_t, int n_nodes) {
  int wave = (blockIdx.x * blockDim.x + threadIdx.x) >> 6;
  int lane = threadIdx.x & 63;
  int nwaves = (gridDim.x * blockDim.x) >> 6;
  int j = lane & 31;
  size_t plane = (size_t)n_nodes * 32;
  const float* Wsel = (lane < 32) ? Wni : Wnj;
  for (int n = wave; n < n_nodes; n += nwaves) {
    const float* hrow = h + (size_t)n * 32;
    float a0 = 0.f, a1 = 0.f, a2 = 0.f;
#pragma unroll
    for (int k = 0; k < 32; k++) {
      float hv = hrow[k];                    // wave-uniform broadcast load
      a0 += hv * Wsel[k * 32 + j];
      a1 += hv * Wnode[k * 128 + lane];
      a2 += hv * Wnode[k * 128 + lane + 64];
    }
    if (lane < 32) fni[(size_t)n * 32 + j] = f2bf(a0);
    else           cdst[(size_t)n * 32 + j] = f2bf(a0 + bE[j]);
    int h0 = lane >> 5;                      // feature lane     -> head 0/1
    int h1 = 2 + (lane >> 5);                // feature lane+64  -> head 2/3
    hh_t[h0 * plane + (size_t)n * 32 + j] = f2bf(a1);
    hh_t[h1 * plane + (size_t)n * 32 + j] = f2bf(a2);
  }
}

// One thread per sorted edge; z written to 4 per-head planes (coalesced).
__global__ void edge_z(const int* __restrict__ src_s,
                       const int* __restrict__ dst_s,
                       const uint4* __restrict__ e_s,        // bf16x8
                       const unsigned short* __restrict__ fni,
                       const unsigned short* __restrict__ cdst,
                       const float* __restrict__ Wf,         // (8,32)
                       const float* __restrict__ attn,       // (32) flat
                       float* __restrict__ zh, int n_edges) {
  __shared__ float wfl[256];
  __shared__ float atl[32];
  int tid = threadIdx.x;
  wfl[tid] = Wf[tid];
  if (tid < 32) atl[tid] = attn[tid];
  __syncthreads();
  int k = blockIdx.x * blockDim.x + tid;
  if (k >= n_edges) return;
  int s = src_s[k], d = dst_s[k];
  uint4 ep = e_s[k];
  float ev[8];
  ev[0] = bf_lo(ep.x); ev[1] = bf_hi(ep.x);
  ev[2] = bf_lo(ep.y); ev[3] = bf_hi(ep.y);
  ev[4] = bf_lo(ep.z); ev[5] = bf_hi(ep.z);
  ev[6] = bf_lo(ep.w); ev[7] = bf_hi(ep.w);
  const uint4* fr = (const uint4*)(fni + (size_t)s * 32);
  const uint4* cr = (const uint4*)(cdst + (size_t)d * 32);
  float f[32];
#pragma unroll
  for (int q = 0; q < 4; q++) {
    uint4 ua = fr[q], ub = cr[q];
    const unsigned* uap = (const unsigned*)&ua;
    const unsigned* ubp = (const unsigned*)&ub;
#pragma unroll
    for (int c = 0; c < 4; c++) {
      int jj = q * 8 + c * 2;
      f[jj]     = bf_lo(uap[c]) + bf_lo(ubp[c]);
      f[jj + 1] = bf_hi(uap[c]) + bf_hi(ubp[c]);
    }
  }
#pragma unroll
  for (int kk = 0; kk < 8; kk++) {
    float ek = ev[kk];
#pragma unroll
    for (int j4 = 0; j4 < 8; j4++) {
      float4 w = ((const float4*)wfl)[kk * 8 + j4];   // ds_read_b128
      f[j4 * 4 + 0] = fmaf(ek, w.x, f[j4 * 4 + 0]);
      f[j4 * 4 + 1] = fmaf(ek, w.y, f[j4 * 4 + 1]);
      f[j4 * 4 + 2] = fmaf(ek, w.z, f[j4 * 4 + 2]);
      f[j4 * 4 + 3] = fmaf(ek, w.w, f[j4 * 4 + 3]);
    }
  }
  float lg[4] = {0.f, 0.f, 0.f, 0.f};
#pragma unroll
  for (int jj = 0; jj < 32; jj++) {
    float t = f[jj];
    t = (t >= 0.f) ? t : 0.01f * t;          // leaky_relu
    lg[jj >> 3] = fmaf(t, atl[jj], lg[jj >> 3]);
  }
  // no max-subtraction: logits are O(1) (0.1-scaled weights, bounded h)
  zh[k]                       = __expf(lg[0]);
  zh[(size_t)n_edges + k]     = __expf(lg[1]);
  zh[2 * (size_t)n_edges + k] = __expf(lg[2]);
  zh[3 * (size_t)n_edges + k] = __expf(lg[3]);
}

// Wave = (node, head). head = (blockIdx%8)>>1 -> XCD-pair L2 affinity for the
// 3.2 MB head slice. 16 lanes per edge (dword = 2 feats), 4 edges in flight.
__global__ void node_agg_head(const float* __restrict__ zh,        // (4,E)
                              const int* __restrict__ src_s,
                              const int* __restrict__ row_off,
                              const unsigned* __restrict__ hh_t,   // (4,N,16) dw
                              unsigned* __restrict__ outh,         // (4,N,16) dw
                              int n_nodes, int n_edges) {
  __shared__ float zb[4][64];
  __shared__ int sb[4][64];
  int wid = threadIdx.x >> 6;
  int lane = threadIdx.x & 63;
  int xcd = blockIdx.x & 7;
  int head = xcd >> 1;
  int i = (blockIdx.x >> 3) * 2 + (xcd & 1);
  int n = i * 4 + wid;
  if (n >= n_nodes) return;
  const float* z = zh + (size_t)head * n_edges;
  const unsigned* hs = hh_t + (size_t)head * n_nodes * 16;
  float* zw = zb[wid];
  int* sw = sb[wid];
  int g = lane >> 4, fl = lane & 15;
  int base = row_off[n], end = row_off[n + 1];
  float accx = 0.f, accy = 0.f, sz = 0.f;

  for (int chunk = base; chunk < end; chunk += 64) {
    int k = chunk + lane;
    float zv = 0.f;
    int sv = 0;
    if (k < end) { zv = z[k]; sv = src_s[k]; }
    zw[lane] = zv;
    sw[lane] = sv;
    sz += zv;
    int cnt = min(64, end - chunk);
    int iters = (cnt + 3) >> 2;
    int ee = 0;
    for (; ee + 4 <= iters; ee += 4) {
      unsigned u[4];
      float zl[4];
#pragma unroll
      for (int t = 0; t < 4; t++) {
        int idx = (ee + t) * 4 + g;          // z=0 pad makes overruns harmless
        zl[t] = zw[idx];
        int ss = sw[idx];
        u[t] = hs[(size_t)ss * 16 + fl];     // 4 independent 64B-line gathers
      }
#pragma unroll
      for (int t = 0; t < 4; t++) {
        accx = fmaf(bf_lo(u[t]), zl[t], accx);
        accy = fmaf(bf_hi(u[t]), zl[t], accy);
      }
    }
    for (; ee < iters; ee++) {
      int idx = ee * 4 + g;
      float zl = zw[idx];
      int ss = sw[idx];
      unsigned u = hs[(size_t)ss * 16 + fl];
      accx = fmaf(bf_lo(u), zl, accx);
      accy = fmaf(bf_hi(u), zl, accy);
    }
  }

  // denom: staged z's summed across the wave
#pragma unroll
  for (int off = 32; off > 0; off >>= 1) sz += __shfl_xor(sz, off);
  // combine the 4 edge-group partials: lanes fl, fl+16, fl+32, fl+48
  accx += __shfl_xor(accx, 16); accx += __shfl_xor(accx, 32);
  accy += __shfl_xor(accy, 16); accy += __shfl_xor(accy, 32);
  if (lane < 16) {
    float ax = 0.f, ay = 0.f;
    if (sz > 0.f) { ax = accx / sz; ay = accy / sz; }
    outh[((size_t)head * n_nodes + n) * 16 + fl] = pack2bf(ax, ay);
  }
}

// Head-sum + ELU; writes hcur (f32) and states (bf16). Thread = (node, 2 feats)
__global__ void combine(const unsigned* __restrict__ outh,
                        float* __restrict__ hcur,
                        unsigned* __restrict__ states_u,   // (N,64) dwords
                        int l, int n_nodes) {
  int idx = blockIdx.x * blockDim.x + threadIdx.x;
  if (idx >= n_nodes * 16) return;
  int n = idx >> 4, fl = idx & 15;
  size_t plane = (size_t)n_nodes * 16;
  unsigned a0 = outh[(size_t)n * 16 + fl];
  unsigned a1 = outh[plane + (size_t)n * 16 + fl];
  unsigned a2 = outh[2 * plane + (size_t)n * 16 + fl];
  unsigned a3 = outh[3 * plane + (size_t)n * 16 + fl];
  float vx = bf_lo(a0) + bf_lo(a1) + bf_lo(a2) + bf_lo(a3);
  float vy = bf_hi(a0) + bf_hi(a1) + bf_hi(a2) + bf_hi(a3);
  float rx = (vx > 0.f) ? vx : expm1f(vx);
  float ry = (vy > 0.f) ? vy : expm1f(vy);
  ((float2*)(hcur + (size_t)n * 32))[fl] = make_float2(rx, ry);
  states_u[(size_t)n * 64 + l * 16 + fl] = pack2bf(rx, ry);
}

// One block (128 threads) per pair; thread t = hidden unit t. states bf16.
__global__ void mlp_head(const unsigned short* __restrict__ states,
                         const int* __restrict__ users, const int* __restrict__ items,
                         const float* __restrict__ W1, const float* __restrict__ b1,
                         const float* __restrict__ W2, const float* __restrict__ b2,
                         float* __restrict__ out, int n_pairs) {
  __shared__ float zin[256];
  __shared__ float red[2];
  int p = blockIdx.x;
  if (p >= n_pairs) return;
  int t = threadIdx.x;
  int u = users[p], it = items[p];
  zin[t] = bf2f(states[(size_t)u * 128 + t]);
  zin[t + 128] = bf2f(states[(size_t)it * 128 + t]);
  __syncthreads();
  float acc = b1[t];
#pragma unroll 8
  for (int i = 0; i < 256; i++) acc += zin[i] * W1[i * 128 + t];
  acc = acc > 0.f ? acc : 0.f;
  float c = acc * W2[t];
#pragma unroll
  for (int off = 32; off > 0; off >>= 1) c += __shfl_down(c, off);
  if ((t & 63) == 0) red[t >> 6] = c;
  __syncthreads();
  if (t == 0) {
    float sum = red[0] + red[1] + b2[0];
    out[p] = 1.f / (1.f + expf(-sum));
  }
}

// ---------------------------------------------------------------------------

extern "C" void kernel_launch(void* const* d_in, const int* in_sizes, int n_in,
                              void* d_out, int out_size, void* d_ws, size_t ws_size,
                              hipStream_t stream) {
  const float* x     = (const float*)d_in[0];
  const float* e     = (const float*)d_in[1];
  const float* W_ni  = (const float*)d_in[2];   // (4,32,32)
  const float* W_nj  = (const float*)d_in[3];   // (4,32,32)
  const float* W_fij = (const float*)d_in[4];   // (4,8,32)
  const float* b_e   = (const float*)d_in[5];   // (4,32)
  const float* attn  = (const float*)d_in[6];   // (4,4,8)
  const float* W_nd  = (const float*)d_in[7];   // (4,32,128)
  const float* W1    = (const float*)d_in[8];   // (256,128)
  const float* b1    = (const float*)d_in[9];   // (128)
  const float* W2    = (const float*)d_in[10];  // (128,1)
  const float* b2    = (const float*)d_in[11];  // (1)
  const int* src   = (const int*)d_in[12];
  const int* dst   = (const int*)d_in[13];
  const int* users = (const int*)d_in[14];
  const int* items = (const int*)d_in[15];
  float* out = (float*)d_out;

  int n_nodes = in_sizes[0] / 32;
  int n_edges = in_sizes[12];
  int n_pairs = in_sizes[14];

  // ---- workspace layout (~116 MB; setup scratch aliased inside outh)
  char* wsb = (char*)d_ws;
  size_t off = 0;
  auto alloc = [&](size_t bytes) {
    char* p = wsb + off;
    off = (off + bytes + 255) & ~(size_t)255;
    return p;
  };
  float*          hcur   = (float*)alloc((size_t)n_nodes * 32 * 4);
  unsigned*       states = (unsigned*)alloc((size_t)n_nodes * 64 * 4);   // bf16 (N,128)
  unsigned short* fni    = (unsigned short*)alloc((size_t)n_nodes * 32 * 2);
  unsigned short* cdst   = (unsigned short*)alloc((size_t)n_nodes * 32 * 2);
  unsigned short* hh_t   = (unsigned short*)alloc((size_t)n_nodes * 128 * 2);
  uint4*          e_s    = (uint4*)alloc((size_t)n_edges * 16);
  float*          zh     = (float*)alloc((size_t)n_edges * 4 * 4);
  unsigned*       outh   = (unsigned*)alloc((size_t)n_nodes * 64 * 4);   // bf16 (4,N,32)
  int*            src_s  = (int*)alloc((size_t)n_edges * 4);
  int*            dst_s  = (int*)alloc((size_t)n_edges * 4);
  int*            row_off  = (int*)alloc(((size_t)n_nodes + 8) * 4);
  int*            blocksum = (int*)alloc(256 * 4);
  // setup-only scratch aliased inside outh (12.8 MB; dead once layers start)
  int* perm   = (int*)outh;                                  // 6.4 MB
  int* hist   = (int*)((char*)outh + ((size_t)n_edges * 4 + 1024));
  int* cursor = (int*)((char*)outh + ((size_t)n_edges * 4 + (size_t)(n_nodes + 16) * 4 + 2048));

  // ---- build CSR-by-dst sorted arrays (once per call)
  int nb = (n_nodes + 1023) / 1024;
  int seg = (n_nodes + FILL_NR - 1) / FILL_NR;
  zero_ints<<<(n_nodes + 255) / 256, 256, 0, stream>>>(hist, n_nodes);
  histogram<<<(n_edges + 255) / 256, 256, 0, stream>>>(dst, hist, n_edges);
  scan_block<<<nb, 1024, 0, stream>>>(hist, row_off, blocksum, n_nodes);
  scan_sums<<<1, 64, 0, stream>>>(blocksum, nb);
  scan_add<<<(n_nodes + 255) / 256, 256, 0, stream>>>(row_off, blocksum, cursor,
                                                      n_nodes, nb);
  fill_perm3<<<2048, 256, 0, stream>>>(dst, src, cursor, perm, src_s, dst_s,
                                       n_edges, seg);
  expand_e<<<(n_edges + 255) / 256, 256, 0, stream>>>(perm, e, e_s, n_edges);

  // ---- layers
  int aggblocks = 8 * ((((n_nodes + 3) / 4) + 1) / 2);
  for (int l = 0; l < 4; l++) {
    const float* hin = (l == 0) ? x : hcur;
    node_proj<<<2048, 256, 0, stream>>>(hin, W_ni + l * 1024, W_nj + l * 1024,
                                        W_nd + l * 4096, b_e + l * 32,
                                        fni, cdst, hh_t, n_nodes);
    edge_z<<<(n_edges + 255) / 256, 256, 0, stream>>>(
        src_s, dst_s, e_s, fni, cdst, W_fij + l * 256, attn + l * 32,
        zh, n_edges);
    node_agg_head<<<aggblocks, 256, 0, stream>>>(
        zh, src_s, row_off, (const unsigned*)hh_t, outh, n_nodes, n_edges);
    combine<<<(n_nodes * 16 + 255) / 256, 256, 0, stream>>>(
        outh, hcur, states, l, n_nodes);
  }
  mlp_head<<<n_pairs, 128, 0, stream>>>((const unsigned short*)states, users,
                                        items, W1, b1, W2, b2, out, n_pairs);
}

// Round 9
// 870.672 us; speedup vs baseline: 1.1322x; 1.1322x over previous
//
#include <hip/hip_runtime.h>
#include <math.h>

// ---------------------------------------------------------------------------
// FGAT round 9: R7 pipeline, setup slimmed.
//   - fill_rec: range-partitioned SINGLE-stream scatter of int2{src,eid}
//     (8 B granule, ~1.6 MB/range -> L2-local line filling; R8's 3-stream
//     version regressed).
//   - dst_s derived from row_off by sequential per-node fill (no scatter).
//   - expand_e: only the e-row gather remains (pack bf16x8, coalesced write).
//   - per-layer kernels: exact R7 (node_proj / edge_z / node_agg, f32 states),
//     src read from rec.x.
// ---------------------------------------------------------------------------

static __device__ inline unsigned short f2bf(float f) {
  unsigned x = __float_as_uint(f);
  unsigned r = x + 0x7fffu + ((x >> 16) & 1u);   // round-to-nearest-even
  return (unsigned short)(r >> 16);
}
static __device__ inline unsigned pack2bf(float lo, float hi) {
  return (unsigned)f2bf(lo) | ((unsigned)f2bf(hi) << 16);
}
static __device__ inline float bf_lo(unsigned u) {
  return __uint_as_float(u << 16);
}
static __device__ inline float bf_hi(unsigned u) {
  return __uint_as_float(u & 0xffff0000u);
}

// ---------------- sort-building kernels ------------------------------------

__global__ void zero_ints(int* __restrict__ p, int n) {
  int i = blockIdx.x * blockDim.x + threadIdx.x;
  if (i < n) p[i] = 0;
}

__global__ void histogram(const int* __restrict__ dst, int* __restrict__ hist,
                          int n_edges) {
  int e = blockIdx.x * blockDim.x + threadIdx.x;
  if (e < n_edges) atomicAdd(&hist[dst[e]], 1);
}

__global__ void scan_block(const int* __restrict__ hist, int* __restrict__ partial,
                           int* __restrict__ blocksum, int n) {
  __shared__ int buf[1024];
  int tid = threadIdx.x;
  int g = blockIdx.x * 1024 + tid;
  int v = (g < n) ? hist[g] : 0;
  buf[tid] = v;
  __syncthreads();
  for (int off = 1; off < 1024; off <<= 1) {
    int t = (tid >= off) ? buf[tid - off] : 0;
    __syncthreads();
    buf[tid] += t;
    __syncthreads();
  }
  if (g < n) partial[g] = buf[tid] - v;       // exclusive within chunk
  if (tid == 1023) blocksum[blockIdx.x] = buf[1023];
}

__global__ void scan_sums(int* __restrict__ blocksum, int nb) {
  if (threadIdx.x == 0 && blockIdx.x == 0) {
    int run = 0;
    for (int i = 0; i < nb; i++) {
      int t = blocksum[i];
      blocksum[i] = run;
      run += t;
    }
    blocksum[nb] = run;
  }
}

__global__ void scan_add(int* __restrict__ partial /* -> row_off */,
                         const int* __restrict__ blocksum,
                         int* __restrict__ cursor, int n, int nb) {
  int g = blockIdx.x * blockDim.x + threadIdx.x;
  if (g < n) {
    int val = partial[g] + blocksum[g >> 10];
    partial[g] = val;
    cursor[g] = val;
  }
  if (g == 0) partial[n] = blocksum[nb];
}

// Range-partitioned fill, single int2{src,eid} scatter stream per edge.
// Per-range rec region ~1.6 MB -> L2-local under blockIdx%8 ~ XCD heuristic
// (mapping is a locality hint only; correctness independent of it).
#define FILL_NR 8
__global__ void fill_rec(const int* __restrict__ dst, const int* __restrict__ src,
                         int* __restrict__ cursor, int2* __restrict__ rec,
                         int n_edges, int seg) {
  int range = blockIdx.x % FILL_NR;
  int group = blockIdx.x / FILL_NR;
  int ngroups = gridDim.x / FILL_NR;
  int lo = range * seg;
  int hi = lo + seg;
  int stride = ngroups * blockDim.x;
  for (int k = group * blockDim.x + threadIdx.x; k < n_edges; k += stride) {
    int d = dst[k];
    if (d >= lo && d < hi) {
      int p = atomicAdd(&cursor[d], 1);
      rec[p] = make_int2(src[k], k);
    }
  }
}

// dst_s[k] = n for k in [row_off[n], row_off[n+1]) — dense ordered writes.
__global__ void dst_fill(const int* __restrict__ row_off, int* __restrict__ dst_s,
                         int n_nodes) {
  int n = blockIdx.x * blockDim.x + threadIdx.x;
  if (n >= n_nodes) return;
  int b = row_off[n], e = row_off[n + 1];
  for (int k = b; k < e; k++) dst_s[k] = n;
}

// Gather e rows through rec.y, pack to bf16x8, coalesced write.
__global__ void expand_e(const int2* __restrict__ rec, const float* __restrict__ e,
                         uint4* __restrict__ e_s, int n_edges) {
  int k = blockIdx.x * blockDim.x + threadIdx.x;
  if (k >= n_edges) return;
  int eid = rec[k].y;
  const float4* ep = (const float4*)(e + (size_t)eid * 8);
  float4 a = ep[0], b = ep[1];
  uint4 r;
  r.x = pack2bf(a.x, a.y); r.y = pack2bf(a.z, a.w);
  r.z = pack2bf(b.x, b.y); r.w = pack2bf(b.z, b.w);
  e_s[k] = r;
}

// ---------------- per-layer kernels ----------------------------------------

// One 64-lane wave per node; bf16 outputs. cdst = fnj + bE (bias folded in).
__global__ void node_proj(const float* __restrict__ h,
                          const float* __restrict__ Wni,
                          const float* __restrict__ Wnj,
                          const float* __restrict__ Wnode,
                          const float* __restrict__ bE,
                          unsigned short* __restrict__ fni,
                          unsigned short* __restrict__ cdst,
                          unsigned short* __restrict__ hh, int n_nodes) {
  int wave = (blockIdx.x * blockDim.x + threadIdx.x) >> 6;
  int lane = threadIdx.x & 63;
  int nwaves = (gridDim.x * blockDim.x) >> 6;
  int j = lane & 31;
  const float* Wsel = (lane < 32) ? Wni : Wnj;
  for (int n = wave; n < n_nodes; n += nwaves) {
    const float* hrow = h + (size_t)n * 32;
    float a0 = 0.f, a1 = 0.f, a2 = 0.f;
#pragma unroll
    for (int k = 0; k < 32; k++) {
      float hv = hrow[k];                    // wave-uniform broadcast load
      a0 += hv * Wsel[k * 32 + j];
      a1 += hv * Wnode[k * 128 + lane];
      a2 += hv * Wnode[k * 128 + lane + 64];
    }
    if (lane < 32) fni[(size_t)n * 32 + j] = f2bf(a0);
    else           cdst[(size_t)n * 32 + j] = f2bf(a0 + bE[j]);
    hh[(size_t)n * 128 + lane] = f2bf(a1);
    hh[(size_t)n * 128 + lane + 64] = f2bf(a2);
  }
}

// One thread per sorted edge: full logit + exp, no cross-lane ops.
__global__ void edge_z(const int2* __restrict__ rec,
                       const int* __restrict__ dst_s,
                       const uint4* __restrict__ e_s,        // bf16x8
                       const unsigned short* __restrict__ fni,
                       const unsigned short* __restrict__ cdst,
                       const float* __restrict__ Wf,         // (8,32)
                       const float* __restrict__ attn,       // (32) flat
                       float4* __restrict__ zrec, int n_edges) {
  __shared__ float wfl[256];
  __shared__ float atl[32];
  int tid = threadIdx.x;
  wfl[tid] = Wf[tid];
  if (tid < 32) atl[tid] = attn[tid];
  __syncthreads();
  int k = blockIdx.x * blockDim.x + tid;
  if (k >= n_edges) return;
  int s = rec[k].x, d = dst_s[k];
  uint4 ep = e_s[k];
  float ev[8];
  ev[0] = bf_lo(ep.x); ev[1] = bf_hi(ep.x);
  ev[2] = bf_lo(ep.y); ev[3] = bf_hi(ep.y);
  ev[4] = bf_lo(ep.z); ev[5] = bf_hi(ep.z);
  ev[6] = bf_lo(ep.w); ev[7] = bf_hi(ep.w);
  const uint4* fr = (const uint4*)(fni + (size_t)s * 32);
  const uint4* cr = (const uint4*)(cdst + (size_t)d * 32);
  float f[32];
#pragma unroll
  for (int q = 0; q < 4; q++) {
    uint4 ua = fr[q], ub = cr[q];
    const unsigned* uap = (const unsigned*)&ua;
    const unsigned* ubp = (const unsigned*)&ub;
#pragma unroll
    for (int c = 0; c < 4; c++) {
      int jj = q * 8 + c * 2;
      f[jj]     = bf_lo(uap[c]) + bf_lo(ubp[c]);
      f[jj + 1] = bf_hi(uap[c]) + bf_hi(ubp[c]);
    }
  }
#pragma unroll
  for (int kk = 0; kk < 8; kk++) {
    float ek = ev[kk];
#pragma unroll
    for (int j4 = 0; j4 < 8; j4++) {
      float4 w = ((const float4*)wfl)[kk * 8 + j4];   // ds_read_b128
      f[j4 * 4 + 0] = fmaf(ek, w.x, f[j4 * 4 + 0]);
      f[j4 * 4 + 1] = fmaf(ek, w.y, f[j4 * 4 + 1]);
      f[j4 * 4 + 2] = fmaf(ek, w.z, f[j4 * 4 + 2]);
      f[j4 * 4 + 3] = fmaf(ek, w.w, f[j4 * 4 + 3]);
    }
  }
  float lg[4] = {0.f, 0.f, 0.f, 0.f};
#pragma unroll
  for (int jj = 0; jj < 32; jj++) {
    float t = f[jj];
    t = (t >= 0.f) ? t : 0.01f * t;          // leaky_relu
    lg[jj >> 3] = fmaf(t, atl[jj], lg[jj >> 3]);
  }
  // no max-subtraction: logits are O(1) (0.1-scaled weights, bounded h)
  zrec[k] = make_float4(__expf(lg[0]), __expf(lg[1]),
                        __expf(lg[2]), __expf(lg[3]));
}

// One wave per node: LDS-staged z/src, scalar-base bf16 hh row gathers with
// 8 loads in flight, denom accumulated at staging time, fused epilogue.
__global__ void node_agg(const float4* __restrict__ zrec,
                         const int2* __restrict__ rec,
                         const int* __restrict__ row_off,
                         const unsigned* __restrict__ hh,   // bf16x2/dword, 64/row
                         float* __restrict__ hcur,
                         float* __restrict__ states,
                         int l, int n_nodes) {
  __shared__ float zw[4][64 * 4];
  __shared__ int sw[4][64];
  int wid = threadIdx.x >> 6;
  int lane = threadIdx.x & 63;
  int n = (blockIdx.x * blockDim.x + threadIdx.x) >> 6;
  if (n >= n_nodes) return;
  int base = row_off[n], end = row_off[n + 1];
  int head = lane >> 4;                      // head of features 2*lane, 2*lane+1
  float* zwf = zw[wid];
  int* swp = sw[wid];
  float accx = 0.f, accy = 0.f;
  float sz0 = 0.f, sz1 = 0.f, sz2 = 0.f, sz3 = 0.f;   // per-lane denom partials

  for (int chunk = base; chunk < end; chunk += 64) {
    int k = chunk + lane;
    float4 zv4 = make_float4(0.f, 0.f, 0.f, 0.f);
    int sv = 0;
    if (k < end) { zv4 = zrec[k]; sv = rec[k].x; }
    ((float4*)zwf)[lane] = zv4;
    swp[lane] = sv;
    sz0 += zv4.x; sz1 += zv4.y; sz2 += zv4.z; sz3 += zv4.w;
    int cnt = min(64, end - chunk);

    int ee = 0;
    for (; ee + 8 <= cnt; ee += 8) {
      unsigned u[8];
      float zl[8];
#pragma unroll
      for (int i = 0; i < 8; i++) {
        int ss = __builtin_amdgcn_readfirstlane(swp[ee + i]);
        zl[i] = zwf[(ee + i) * 4 + head];
        u[i] = hh[(size_t)ss * 64 + lane];   // 8 independent gathers in flight
      }
#pragma unroll
      for (int i = 0; i < 8; i++) {
        accx = fmaf(bf_lo(u[i]), zl[i], accx);
        accy = fmaf(bf_hi(u[i]), zl[i], accy);
      }
    }
    for (; ee < cnt; ee++) {
      int ss = __builtin_amdgcn_readfirstlane(swp[ee]);
      float zv = zwf[ee * 4 + head];
      unsigned u = hh[(size_t)ss * 64 + lane];
      accx = fmaf(bf_lo(u), zv, accx);
      accy = fmaf(bf_hi(u), zv, accy);
    }
  }

  // butterfly-sum denom partials across the wave
#pragma unroll
  for (int off = 32; off > 0; off >>= 1) {
    sz0 += __shfl_xor(sz0, off); sz1 += __shfl_xor(sz1, off);
    sz2 += __shfl_xor(sz2, off); sz3 += __shfl_xor(sz3, off);
  }
  float dh = (head == 0) ? sz0 : (head == 1) ? sz1 : (head == 2) ? sz2 : sz3;

  float vx = 0.f, vy = 0.f;
  if (dh > 0.f) { vx = accx / dh; vy = accy / dh; }
  // sum 4 heads: partners at lane^16, lane^32
  vx += __shfl_xor(vx, 16); vx += __shfl_xor(vx, 32);
  vy += __shfl_xor(vy, 16); vy += __shfl_xor(vy, 32);
  if (lane < 16) {
    float rx = (vx > 0.f) ? vx : expm1f(vx);
    float ry = (vy > 0.f) ? vy : expm1f(vy);
    float2 r = make_float2(rx, ry);
    ((float2*)(hcur + (size_t)n * 32))[lane] = r;
    ((float2*)(states + (size_t)n * 128 + l * 32))[lane] = r;
  }
}

// One block (128 threads) per pair; thread t = hidden unit t.
__global__ void mlp_head(const float* __restrict__ states,
                         const int* __restrict__ users, const int* __restrict__ items,
                         const float* __restrict__ W1, const float* __restrict__ b1,
                         const float* __restrict__ W2, const float* __restrict__ b2,
                         float* __restrict__ out, int n_pairs) {
  __shared__ float zin[256];
  __shared__ float red[2];
  int p = blockIdx.x;
  if (p >= n_pairs) return;
  int t = threadIdx.x;
  int u = users[p], it = items[p];
  zin[t] = states[(size_t)u * 128 + t];
  zin[t + 128] = states[(size_t)it * 128 + t];
  __syncthreads();
  float acc = b1[t];
#pragma unroll 8
  for (int i = 0; i < 256; i++) acc += zin[i] * W1[i * 128 + t];
  acc = acc > 0.f ? acc : 0.f;
  float c = acc * W2[t];
#pragma unroll
  for (int off = 32; off > 0; off >>= 1) c += __shfl_down(c, off);
  if ((t & 63) == 0) red[t >> 6] = c;
  __syncthreads();
  if (t == 0) {
    float sum = red[0] + red[1] + b2[0];
    out[p] = 1.f / (1.f + expf(-sum));
  }
}

// ---------------------------------------------------------------------------

extern "C" void kernel_launch(void* const* d_in, const int* in_sizes, int n_in,
                              void* d_out, int out_size, void* d_ws, size_t ws_size,
                              hipStream_t stream) {
  const float* x     = (const float*)d_in[0];
  const float* e     = (const float*)d_in[1];
  const float* W_ni  = (const float*)d_in[2];   // (4,32,32)
  const float* W_nj  = (const float*)d_in[3];   // (4,32,32)
  const float* W_fij = (const float*)d_in[4];   // (4,8,32)
  const float* b_e   = (const float*)d_in[5];   // (4,32)
  const float* attn  = (const float*)d_in[6];   // (4,4,8)
  const float* W_nd  = (const float*)d_in[7];   // (4,32,128)
  const float* W1    = (const float*)d_in[8];   // (256,128)
  const float* b1    = (const float*)d_in[9];   // (128)
  const float* W2    = (const float*)d_in[10];  // (128,1)
  const float* b2    = (const float*)d_in[11];  // (1)
  const int* src   = (const int*)d_in[12];
  const int* dst   = (const int*)d_in[13];
  const int* users = (const int*)d_in[14];
  const int* items = (const int*)d_in[15];
  float* out = (float*)d_out;

  int n_nodes = in_sizes[0] / 32;
  int n_edges = in_sizes[12];
  int n_pairs = in_sizes[14];

  // ---- workspace layout (~122 MB; setup scratch aliased inside zrec)
  char* wsb = (char*)d_ws;
  size_t off = 0;
  auto alloc = [&](size_t bytes) {
    char* p = wsb + off;
    off = (off + bytes + 255) & ~(size_t)255;
    return p;
  };
  float*          hcur   = (float*)alloc((size_t)n_nodes * 32 * 4);
  float*          states = (float*)alloc((size_t)n_nodes * 128 * 4);
  unsigned short* fni    = (unsigned short*)alloc((size_t)n_nodes * 32 * 2);
  unsigned short* cdst   = (unsigned short*)alloc((size_t)n_nodes * 32 * 2);
  unsigned short* hh     = (unsigned short*)alloc((size_t)n_nodes * 128 * 2);
  uint4*          e_s    = (uint4*)alloc((size_t)n_edges * 16);
  float4*         zrec   = (float4*)alloc((size_t)n_edges * 16);
  int2*           rec    = (int2*)alloc((size_t)n_edges * 8);
  int*            dst_s  = (int*)alloc((size_t)n_edges * 4);
  int*            row_off  = (int*)alloc(((size_t)n_nodes + 8) * 4);
  int*            blocksum = (int*)alloc(256 * 4);
  // setup-only scratch aliased inside zrec (dead until edge_z runs):
  int* hist   = (int*)zrec;
  int* cursor = (int*)((char*)zrec + (size_t)(n_nodes + 16) * 4);

  // ---- build CSR-by-dst sorted records (once per call)
  int nb = (n_nodes + 1023) / 1024;
  int seg = (n_nodes + FILL_NR - 1) / FILL_NR;
  zero_ints<<<(n_nodes + 255) / 256, 256, 0, stream>>>(hist, n_nodes);
  histogram<<<(n_edges + 255) / 256, 256, 0, stream>>>(dst, hist, n_edges);
  scan_block<<<nb, 1024, 0, stream>>>(hist, row_off, blocksum, n_nodes);
  scan_sums<<<1, 64, 0, stream>>>(blocksum, nb);
  scan_add<<<(n_nodes + 255) / 256, 256, 0, stream>>>(row_off, blocksum, cursor,
                                                      n_nodes, nb);
  fill_rec<<<2048, 256, 0, stream>>>(dst, src, cursor, rec, n_edges, seg);
  dst_fill<<<(n_nodes + 255) / 256, 256, 0, stream>>>(row_off, dst_s, n_nodes);
  expand_e<<<(n_edges + 255) / 256, 256, 0, stream>>>(rec, e, e_s, n_edges);

  // ---- layers
  for (int l = 0; l < 4; l++) {
    const float* hin = (l == 0) ? x : hcur;
    node_proj<<<2048, 256, 0, stream>>>(hin, W_ni + l * 1024, W_nj + l * 1024,
                                        W_nd + l * 4096, b_e + l * 32,
                                        fni, cdst, hh, n_nodes);
    edge_z<<<(n_edges + 255) / 256, 256, 0, stream>>>(
        rec, dst_s, e_s, fni, cdst, W_fij + l * 256, attn + l * 32,
        zrec, n_edges);
    node_agg<<<(n_nodes * 64 + 255) / 256, 256, 0, stream>>>(
        zrec, rec, row_off, (const unsigned*)hh, hcur, states, l, n_nodes);
  }
  mlp_head<<<n_pairs, 128, 0, stream>>>(states, users, items, W1, b1, W2, b2,
                                        out, n_pairs);
}